// Round 2
// baseline (299.522 us; speedup 1.0000x reference)
//
#include <hip/hip_runtime.h>
#include <hip/hip_bf16.h>

typedef __attribute__((ext_vector_type(8))) short s8v;    // 8 bf16
typedef __attribute__((ext_vector_type(4))) short s4v;    // 4 bf16
typedef __attribute__((ext_vector_type(4))) float f4v;    // 4 fp32

__device__ __forceinline__ void g2lds16(const void* g, void* l) {
  __builtin_amdgcn_global_load_lds(
      (__attribute__((address_space(1))) void*)(g),
      (__attribute__((address_space(3))) void*)(l), 16, 0, 0);
}

__device__ __forceinline__ short f2bf(float f) {
  __hip_bfloat16 h = __float2bfloat16(f);
  return *reinterpret_cast<short*>(&h);
}

// ---------------- K0a: x fp32 -> bf16 ----------------
__global__ void k_cvt_x(const float* __restrict__ x, __hip_bfloat16* __restrict__ xb) {
  int i = (blockIdx.x * 256 + threadIdx.x) * 4;
  float4 v = *(const float4*)(x + i);
  __hip_bfloat16 o[4] = {__float2bfloat16(v.x), __float2bfloat16(v.y),
                         __float2bfloat16(v.z), __float2bfloat16(v.w)};
  *(uint2*)(xb + i) = *(const uint2*)(o);
}

// ---------------- K0b: W [1024,3072] fp32 -> Wt [3072,1024] bf16 ----------------
__global__ void k_transpose_w(const float* __restrict__ W, __hip_bfloat16* __restrict__ Wt) {
  __shared__ float tile[32][33];
  int c0 = blockIdx.x * 32;   // over 3072
  int r0 = blockIdx.y * 32;   // over 1024
  int tr = threadIdx.x >> 5;  // 0..7
  int tc = threadIdx.x & 31;
#pragma unroll
  for (int i = 0; i < 32; i += 8)
    tile[tr + i][tc] = W[(size_t)(r0 + tr + i) * 3072 + c0 + tc];
  __syncthreads();
#pragma unroll
  for (int i = 0; i < 32; i += 8)
    Wt[(size_t)(c0 + tr + i) * 1024 + r0 + tc] = __float2bfloat16(tile[tc][tr + i]);
}

// ---------------- K1: GEMM  Y[4096,3072] = A[4096,1024] @ Wt^T, + bias, bf16 out ----
__global__ __launch_bounds__(256) void k_gemm(const __hip_bfloat16* __restrict__ A,
                                              const __hip_bfloat16* __restrict__ Bt,
                                              const float* __restrict__ bias,
                                              __hip_bfloat16* __restrict__ Y) {
  __shared__ __align__(16) __hip_bfloat16 As[128 * 32];
  __shared__ __align__(16) __hip_bfloat16 Bs[128 * 32];
  const int tid = threadIdx.x;
  const int lane = tid & 63, wave = tid >> 6;
  const int m0 = blockIdx.y * 128, n0 = blockIdx.x * 128;
  const int wm = (wave & 1) * 64, wn = (wave >> 1) * 64;
  const int lrow = lane & 15, lk = (lane >> 4) * 8;

  f4v acc[4][4] = {};

  for (int k0 = 0; k0 < 1024; k0 += 32) {
#pragma unroll
    for (int c = 0; c < 2; ++c) {
      int e = c * 2048 + tid * 8;
      int row = e >> 5, col = e & 31;
      g2lds16(A + (size_t)(m0 + row) * 1024 + k0 + col, As + e);
      g2lds16(Bt + (size_t)(n0 + row) * 1024 + k0 + col, Bs + e);
    }
    __syncthreads();
    s8v af[4], bfr[4];
#pragma unroll
    for (int mi = 0; mi < 4; ++mi) af[mi] = *(const s8v*)(As + (wm + mi * 16 + lrow) * 32 + lk);
#pragma unroll
    for (int ni = 0; ni < 4; ++ni) bfr[ni] = *(const s8v*)(Bs + (wn + ni * 16 + lrow) * 32 + lk);
#pragma unroll
    for (int mi = 0; mi < 4; ++mi)
#pragma unroll
      for (int ni = 0; ni < 4; ++ni)
        acc[mi][ni] = __builtin_amdgcn_mfma_f32_16x16x32_bf16(af[mi], bfr[ni], acc[mi][ni], 0, 0, 0);
    __syncthreads();
  }

#pragma unroll
  for (int mi = 0; mi < 4; ++mi) {
    int r = m0 + wm + mi * 16 + (lane >> 4) * 4;
#pragma unroll
    for (int ni = 0; ni < 4; ++ni) {
      int c = n0 + wn + ni * 16 + lrow;
      float bv = bias[c];
#pragma unroll
      for (int reg = 0; reg < 4; ++reg)
        Y[(size_t)(r + reg) * 3072 + c] = __float2bfloat16(acc[mi][ni][reg] + bv);
    }
  }
}

// ---------------- K2: gather y -> Q [b,h,t,d], K [b,h,t,d], Vt [b,h,d,t] ----------
__global__ void k_gather(const __hip_bfloat16* __restrict__ y,
                         __hip_bfloat16* __restrict__ Q,
                         __hip_bfloat16* __restrict__ K,
                         __hip_bfloat16* __restrict__ Vt) {
  __shared__ __align__(16) __hip_bfloat16 lds[16 * 1028];  // rows padded 1024->1028
  int bx = blockIdx.x;
  int s = bx >> 8, rem = bx & 255, b = rem >> 7, tc = rem & 127;
  const __hip_bfloat16* src = y + (size_t)s * 4194304 + (size_t)b * 2097152 + (size_t)tc * 16384;
  for (int c = threadIdx.x; c < 4096; c += 256) {  // 4-bf16 (8B) chunks
    int tt = c >> 8, jc = c & 255;
    *(uint2*)(lds + tt * 1028 + jc * 4) = *(const uint2*)(src + tt * 1024 + jc * 4);
  }
  __syncthreads();
  size_t hb = (size_t)b * 16 * 131072;
  if (s < 2) {
    __hip_bfloat16* dst = (s == 0) ? Q : K;
    for (int e = threadIdx.x; e < 16384; e += 256) {
      int h = e >> 10, r = e & 1023;
      int tt = r >> 6, d = r & 63;
      dst[hb + (size_t)h * 131072 + (size_t)(tc * 16 + tt) * 64 + d] = lds[tt * 1028 + d * 16 + h];
    }
  } else {
    for (int e = threadIdx.x; e < 16384; e += 256) {
      int h = e >> 10, r = e & 1023;
      int d = r >> 4, tt = r & 15;
      Vt[hb + (size_t)h * 131072 + (size_t)d * 2048 + tc * 16 + tt] = lds[tt * 1028 + d * 16 + h];
    }
  }
}

// ---------------- K3: causal flash attention, S^T form, barrier-free inner loop ----
// One wave (64 thr) per block; wave owns 32 Q rows of one (b,h).
// S^T = MFMA(A=K, B=Q): C layout row=s=quad*4+reg, col=t=lane&15  -> softmax per-lane.
// P (C-layout) is directly the B operand of mfma_f32_16x16x16_bf16 (k=quad*4+j).
// O^T[d,t] accumulated; alpha is per-lane scalar.
__global__ __launch_bounds__(64, 2) void k_attn(const __hip_bfloat16* __restrict__ Q,
                                                const __hip_bfloat16* __restrict__ K,
                                                const __hip_bfloat16* __restrict__ Vt,
                                                float* __restrict__ out) {
  __shared__ float Osh[32 * 66];
  const int lane = threadIdx.x;
  const int l = lane & 15, q = lane >> 4;
  const int qb = 63 - (int)blockIdx.x;   // heavy blocks first
  const int bh = blockIdx.y;
  const int jl = qb >> 1;                // last KV tile index

  const __hip_bfloat16* Kp = K + (size_t)bh * 131072;
  const __hip_bfloat16* Vp = Vt + (size_t)bh * 131072;
  const __hip_bfloat16* Qp = Q + (size_t)bh * 131072;

  // Q B-fragments (load once): B[n=t][k], t = qb*32 + tt*16 + l, k = kh*32 + q*8 ..
  s8v Qf[2][2];
#pragma unroll
  for (int tt = 0; tt < 2; ++tt)
#pragma unroll
    for (int kh = 0; kh < 2; ++kh)
      Qf[tt][kh] = *(const s8v*)(Qp + (size_t)(qb * 32 + tt * 16 + l) * 64 + kh * 32 + q * 8);

  f4v O[2][4] = {};
  float m2[2] = {-INFINITY, -INFINITY};
  float lsum[2] = {0.f, 0.f};
  const float c1 = 0.125f * 1.44269504088896f;  // scale * log2(e)

  auto loadK = [&](int j, s8v(&KF)[4][2]) {
#pragma unroll
    for (int nt = 0; nt < 4; ++nt)
#pragma unroll
      for (int kh = 0; kh < 2; ++kh)
        KF[nt][kh] = *(const s8v*)(Kp + (size_t)j * 4096 + (nt * 16 + l) * 64 + kh * 32 + q * 8);
  };

  auto step = [&](int j, s8v(&KC)[4][2], s8v(&KN)[4][2]) {
    // V fragments for this tile: A[m=d][k=s], d = dt*16+l, s = sc*16 + q*4 ..
    s4v Vf[4][4];
#pragma unroll
    for (int sc = 0; sc < 4; ++sc)
#pragma unroll
      for (int dt = 0; dt < 4; ++dt)
        Vf[sc][dt] = *(const s4v*)(Vp + (size_t)(dt * 16 + l) * 2048 + j * 64 + sc * 16 + q * 4);
    // prefetch next K tile
    int jn = (j + 1 <= jl) ? j + 1 : jl;
    loadK(jn, KN);
    const bool diag = (j == jl);

#pragma unroll
    for (int tt = 0; tt < 2; ++tt) {
      f4v S[4];
#pragma unroll
      for (int nt = 0; nt < 4; ++nt) {
        f4v z = {0.f, 0.f, 0.f, 0.f};
        z = __builtin_amdgcn_mfma_f32_16x16x32_bf16(KC[nt][0], Qf[tt][0], z, 0, 0, 0);
        z = __builtin_amdgcn_mfma_f32_16x16x32_bf16(KC[nt][1], Qf[tt][1], z, 0, 0, 0);
        S[nt] = z;
      }
      float p2[4][4];
#pragma unroll
      for (int nt = 0; nt < 4; ++nt)
#pragma unroll
        for (int r = 0; r < 4; ++r) p2[nt][r] = S[nt][r] * c1;
      if (diag) {
        int tg = qb * 32 + tt * 16 + l;
#pragma unroll
        for (int nt = 0; nt < 4; ++nt)
#pragma unroll
          for (int r = 0; r < 4; ++r)
            if (j * 64 + nt * 16 + q * 4 + r > tg) p2[nt][r] = -1e30f;
      }
      // row max: in-lane over 16 regs, then cross-quad (2 shuffles)
      float mx = p2[0][0];
#pragma unroll
      for (int nt = 0; nt < 4; ++nt)
#pragma unroll
        for (int r = 0; r < 4; ++r) mx = fmaxf(mx, p2[nt][r]);
      mx = fmaxf(mx, __shfl_xor(mx, 16));
      mx = fmaxf(mx, __shfl_xor(mx, 32));
      float mn = fmaxf(m2[tt], mx);
      float alpha = exp2f(m2[tt] - mn);
      m2[tt] = mn;
      float rs = 0.f;
      s4v Pf[4];
#pragma unroll
      for (int nt = 0; nt < 4; ++nt)
#pragma unroll
        for (int r = 0; r < 4; ++r) {
          float e = exp2f(p2[nt][r] - mn);
          rs += e;
          Pf[nt][r] = f2bf(e);
        }
      rs += __shfl_xor(rs, 16);
      rs += __shfl_xor(rs, 32);
      lsum[tt] = lsum[tt] * alpha + rs;
#pragma unroll
      for (int dt = 0; dt < 4; ++dt) O[tt][dt] *= alpha;
#pragma unroll
      for (int sc = 0; sc < 4; ++sc)
#pragma unroll
        for (int dt = 0; dt < 4; ++dt)
          O[tt][dt] = __builtin_amdgcn_mfma_f32_16x16x16bf16_1k(Vf[sc][dt], Pf[sc], O[tt][dt], 0, 0, 0);
    }
  };

  s8v Ka[4][2], Kb[4][2];
  loadK(0, Ka);
  for (int j = 0; j <= jl; j += 2) {
    step(j, Ka, Kb);
    if (j + 1 <= jl) step(j + 1, Kb, Ka);
  }

  // epilogue: O^T -> LDS -> coalesced fp32 stores
  float inv[2] = {1.f / lsum[0], 1.f / lsum[1]};
#pragma unroll
  for (int tt = 0; tt < 2; ++tt)
#pragma unroll
    for (int dt = 0; dt < 4; ++dt)
#pragma unroll
      for (int r = 0; r < 4; ++r)
        Osh[(tt * 16 + l) * 66 + dt * 16 + q * 4 + r] = O[tt][dt][r] * inv[tt];
  __syncthreads();
  int b = bh >> 4, h = bh & 15;
  float* ob = out + ((size_t)b * 2048 + qb * 32) * 1024 + h * 64;
  int r0 = lane >> 1, half = lane & 1;
#pragma unroll
  for (int i = 0; i < 8; ++i) {
    float2 u = *(float2*)&Osh[r0 * 66 + half * 32 + i * 4];
    float2 w = *(float2*)&Osh[r0 * 66 + half * 32 + i * 4 + 2];
    float4 v4 = {u.x, u.y, w.x, w.y};
    *(float4*)&ob[(size_t)r0 * 1024 + half * 32 + i * 4] = v4;
  }
}

extern "C" void kernel_launch(void* const* d_in, const int* in_sizes, int n_in,
                              void* d_out, int out_size, void* d_ws, size_t ws_size,
                              hipStream_t stream) {
  const float* x = (const float*)d_in[0];     // [2,2048,1024]
  const float* W = (const float*)d_in[1];     // [1024,3072]
  const float* bias = (const float*)d_in[2];  // [3072]
  float* out = (float*)d_out;                 // [2,2048,1024]

  char* ws = (char*)d_ws;
  __hip_bfloat16* xb = (__hip_bfloat16*)ws;                           // 8,388,608 B
  __hip_bfloat16* Wt = (__hip_bfloat16*)(ws + 8388608);               // 6,291,456 B
  __hip_bfloat16* y  = (__hip_bfloat16*)(ws + 8388608 + 6291456);     // 25,165,824 B
  __hip_bfloat16* Qg = (__hip_bfloat16*)(ws + 39845888);              // 8,388,608 B
  __hip_bfloat16* Kg = (__hip_bfloat16*)(ws + 48234496);              // 8,388,608 B
  __hip_bfloat16* Vt = (__hip_bfloat16*)(ws + 56623104);              // 8,388,608 B

  k_cvt_x<<<4096, 256, 0, stream>>>(x, xb);
  k_transpose_w<<<dim3(96, 32), 256, 0, stream>>>(W, Wt);
  k_gemm<<<dim3(24, 32), 256, 0, stream>>>(xb, Wt, bias, y);
  k_gather<<<768, 256, 0, stream>>>(y, Qg, Kg, Vt);
  k_attn<<<dim3(64, 32), 64, 0, stream>>>(Qg, Kg, Vt, out);
}